// Round 1
// baseline (608.123 us; speedup 1.0000x reference)
//
#include <hip/hip_runtime.h>

namespace {

constexpr float C2  = 0.2f;   // DT/DX^2 (stencil coefficient)
constexpr float DTC = 0.2f;   // DT
constexpr float IDT = 5.0f;   // 1/DT

// XOR-swizzled LDS layout: float4 unit q (0..15) of row (0..63) lives at
// float4-index row*16 + (q ^ (row&15)). Spreads b128 bank-starts across all
// 8 4-bank groups for wave-wide row reads (rows differ by 1 inside a wave).
__device__ __forceinline__ int ldsOff(int row, int q) {
    return ((row << 4) + (q ^ (row & 15))) << 2;   // float offset
}

__global__ __launch_bounds__(512, 2)
void fused_scan(const float* __restrict__ W, float* __restrict__ out) {
    __shared__ float sxi[4096];
    __shared__ float s4[4096];
    __shared__ float s5[4096];
    __shared__ float s6[4096];

    const int tid = threadIdx.x;
    const int b   = blockIdx.x;
    const int x   = tid >> 3;      // row 0..63
    const int ycc = tid & 7;       // y-chunk 0..7 (8 consecutive y each)
    const int yo  = ycc << 3;      // first y of this thread
    const int q0  = ycc << 1;      // first float4 index within row

    // wave = 8 consecutive rows x 8 y-chunks; y+-1 neighbors are in-wave
    const int lane   = tid & 63;
    const int laneYm = (lane & 56) | ((ycc - 1) & 7);
    const int laneYp = (lane & 56) | ((ycc + 1) & 7);

    const int xm  = (x + 63) & 63;
    const int xp  = (x + 1) & 63;
    const int i2r = (x == 0) ? 62 : (x - 1);   // I2 source row (x=63 -> 62 too)

    const bool xedge = (x == 0) || (x == 63);
    const bool crn0  = xedge && (ycc == 0);    // j==0 is a grid corner
    const bool crn7  = xedge && (ycc == 7);    // j==7 is a grid corner

    float cxi[8], c4[8], c5[8], c6[8], xprev[8], wprev[8];
    #pragma unroll
    for (int j = 0; j < 8; ++j) {
        cxi[j] = 0.0f; c4[j] = 0.0f; c5[j] = 0.0f; c6[j] = 0.0f;
        xprev[j] = 0.0f; wprev[j] = 0.0f;
    }

    const float4 z4 = make_float4(0.0f, 0.0f, 0.0f, 0.0f);
    #pragma unroll
    for (int h = 0; h < 2; ++h) {
        *(float4*)&sxi[ldsOff(x, q0 + h)] = z4;
        *(float4*)&s4 [ldsOff(x, q0 + h)] = z4;
        *(float4*)&s5 [ldsOff(x, q0 + h)] = z4;
        *(float4*)&s6 [ldsOff(x, q0 + h)] = z4;
    }
    __syncthreads();

    const float* Wb = W   + (size_t)b * 64 * 4096;
    float*       oB = out + (size_t)b * 64 * 4096 * 7;

    for (int t = 0; t < 64; ++t) {
        // ---- W slice (own 8 floats), dW ----
        const float* wp = Wb + t * 4096 + x * 64 + yo;
        float wt[8];
        *(float4*)&wt[0] = *(const float4*)(wp);
        *(float4*)&wt[4] = *(const float4*)(wp + 4);

        float dw[8];
        #pragma unroll
        for (int j = 0; j < 8; ++j)
            dw[j] = (t == 0) ? 0.0f : (wt[j] - wprev[j]) * IDT;
        #pragma unroll
        for (int j = 0; j < 8; ++j) wprev[j] = wt[j];

        // ---- I2 source row of I_xi (state at time t) ----
        float xi2[8];
        *(float4*)&xi2[0] = *(const float4*)&sxi[ldsOff(i2r, q0)];
        *(float4*)&xi2[4] = *(const float4*)&sxi[ldsOff(i2r, q0 + 1)];

        // ---- write the 7 channels at time t (56 contiguous aligned floats) ----
        #pragma unroll
        for (int h = 0; h < 2; ++h) {
            float4 ov[7];
            float* o = (float*)ov;
            #pragma unroll
            for (int j = 0; j < 4; ++j) {
                const int jj = (h << 2) + j;
                o[j * 7 + 0] = dw[jj];
                o[j * 7 + 1] = cxi[jj];
                o[j * 7 + 2] = (t == 0) ? 0.0f : -xprev[jj];  // I1; t=0 fixed later
                o[j * 7 + 3] = -xi2[jj];                      // I2
                o[j * 7 + 4] = c4[jj];
                o[j * 7 + 5] = c5[jj];
                o[j * 7 + 6] = c6[jj];
            }
            float4* dst = (float4*)(oB + ((size_t)t * 4096 + x * 64 + yo + (h << 2)) * 7);
            #pragma unroll
            for (int k = 0; k < 7; ++k) dst[k] = ov[k];
        }

        if (t == 63) {
            // deferred: ch2 at t=0 is -I_xi[62] = -xprev (same thread overwrites)
            float* p0 = oB + (size_t)(x * 64 + yo) * 7 + 2;
            #pragma unroll
            for (int j = 0; j < 8; ++j) p0[j * 7] = -xprev[j];
        } else {
            // ---- forcings at time t ----
            float g4v[8], g5v[8], g6v[8];
            #pragma unroll
            for (int j = 0; j < 8; ++j) {
                g4v[j] = dw[j] * cxi[j];          // dW * I_xi
                g5v[j] = cxi[j] * cxi[j];         // I_xi^2
                g6v[j] = xprev[j] * xi2[j];       // (-I_xi[t-1]) * (-shift(I_xi[t]))
            }
            #pragma unroll
            for (int j = 0; j < 8; ++j) xprev[j] = cxi[j];

            // ---- one explicit-Euler step per field ----
            auto stepField = [&](const float* sArr, float* c, const float* g) {
                float nb[16];
                *(float4*)&nb[0]  = *(const float4*)&sArr[ldsOff(xm, q0)];
                *(float4*)&nb[4]  = *(const float4*)&sArr[ldsOff(xm, q0 + 1)];
                *(float4*)&nb[8]  = *(const float4*)&sArr[ldsOff(xp, q0)];
                *(float4*)&nb[12] = *(const float4*)&sArr[ldsOff(xp, q0 + 1)];
                const float ym = __shfl(c[7], laneYm, 64);   // u[x, yo-1] (periodic)
                const float yp = __shfl(c[0], laneYp, 64);   // u[x, yo+8] (periodic)
                float n[8];
                #pragma unroll
                for (int j = 0; j < 8; ++j) {
                    const float left  = (j == 0) ? ym : c[j - 1];
                    const float right = (j == 7) ? yp : c[j + 1];
                    float lap = nb[j] + nb[8 + j] + left + right - 4.0f * c[j];
                    if ((j == 0 && crn0) || (j == 7 && crn7)) lap = 0.0f; // corners
                    n[j] = c[j] + C2 * lap + g[j] * DTC;
                }
                #pragma unroll
                for (int j = 0; j < 8; ++j) c[j] = n[j];
            };

            stepField(sxi, cxi, dw);
            stepField(s4,  c4,  g4v);
            stepField(s5,  c5,  g5v);
            stepField(s6,  c6,  g6v);

            __syncthreads();   // all LDS reads of state t done
            #pragma unroll
            for (int h = 0; h < 2; ++h) {
                *(float4*)&sxi[ldsOff(x, q0 + h)] = *(float4*)&cxi[h << 2];
                *(float4*)&s4 [ldsOff(x, q0 + h)] = *(float4*)&c4 [h << 2];
                *(float4*)&s5 [ldsOff(x, q0 + h)] = *(float4*)&c5 [h << 2];
                *(float4*)&s6 [ldsOff(x, q0 + h)] = *(float4*)&c6 [h << 2];
            }
            __syncthreads();   // state t+1 visible to all
        }
    }
}

} // namespace

extern "C" void kernel_launch(void* const* d_in, const int* in_sizes, int n_in,
                              void* d_out, int out_size, void* d_ws, size_t ws_size,
                              hipStream_t stream) {
    const float* W  = (const float*)d_in[0];
    float* out      = (float*)d_out;
    hipLaunchKernelGGL(fused_scan, dim3(32), dim3(512), 0, stream, W, out);
}

// Round 2
// 341.732 us; speedup vs baseline: 1.7795x; 1.7795x over previous
//
#include <hip/hip_runtime.h>

namespace {

constexpr float C2  = 0.2f;   // DT/DX^2 (stencil coefficient)
constexpr float DTC = 0.2f;   // DT
constexpr float IDT = 5.0f;   // 1/DT

// XOR-swizzled LDS layout: float4 unit q (0..15) of row (0..63) lives at
// float4-index row*16 + (q ^ (row&15)). Spreads b128 bank-starts across all
// 8 4-bank groups for wave-wide row reads (rows differ by 1 inside a wave).
__device__ __forceinline__ int ldsOff(int row, int q) {
    return ((row << 4) + (q ^ (row & 15))) << 2;   // float offset
}

// 256 blocks = 8 "parts" per batch. Every block runs the full 4-field scan
// (bitwise-identical redundant compute); block `part` stores only x-rows
// [8*part, 8*part+8) -> per-CU store traffic drops 8x (round-1 wall was the
// ~17 GB/s/CU store drain with only 32 CUs active).
__global__ __launch_bounds__(512, 2)
void fused_scan(const float* __restrict__ W, float* __restrict__ out) {
    // double-buffered scan state: one barrier per iteration. 128 KB LDS also
    // pins 1 block/CU so 256 blocks spread over all 256 CUs.
    __shared__ float sxi[2][4096];
    __shared__ float s4 [2][4096];
    __shared__ float s5 [2][4096];
    __shared__ float s6 [2][4096];

    const int tid  = threadIdx.x;
    const int b    = blockIdx.x >> 3;
    const int part = blockIdx.x & 7;

    const int x   = tid >> 3;      // row 0..63
    const int ycc = tid & 7;       // y-chunk 0..7 (8 consecutive y each)
    const int yo  = ycc << 3;      // first y of this thread
    const int q0  = ycc << 1;      // first float4 index within row

    const bool mine = ((tid >> 6) == part);   // wave-uniform store guard

    // wave = 8 consecutive rows x 8 y-chunks; y+-1 neighbors are in-wave
    const int lane   = tid & 63;
    const int laneYm = (lane & 56) | ((ycc - 1) & 7);
    const int laneYp = (lane & 56) | ((ycc + 1) & 7);

    const int xm = (x + 63) & 63;
    const int xp = (x + 1) & 63;
    // I2 source row: x-1 for x>0 (== xm), row 62 for x==0 (and x==63's xm==62 too)

    const bool xedge = (x == 0) || (x == 63);
    const bool crn0  = xedge && (ycc == 0);    // j==0 is a grid corner
    const bool crn7  = xedge && (ycc == 7);    // j==7 is a grid corner

    float cxi[8], c4[8], c5[8], c6[8], xprev[8], wprev[8];
    #pragma unroll
    for (int j = 0; j < 8; ++j) {
        cxi[j] = 0.0f; c4[j] = 0.0f; c5[j] = 0.0f; c6[j] = 0.0f;
        xprev[j] = 0.0f; wprev[j] = 0.0f;
    }

    const float4 z4 = make_float4(0.0f, 0.0f, 0.0f, 0.0f);
    #pragma unroll
    for (int h = 0; h < 2; ++h) {
        *(float4*)&sxi[0][ldsOff(x, q0 + h)] = z4;
        *(float4*)&s4 [0][ldsOff(x, q0 + h)] = z4;
        *(float4*)&s5 [0][ldsOff(x, q0 + h)] = z4;
        *(float4*)&s6 [0][ldsOff(x, q0 + h)] = z4;
    }
    __syncthreads();

    const float* Wb = W   + (size_t)b * 64 * 4096;
    float*       oB = out + (size_t)b * 64 * 4096 * 7;

    // prefetch W slice for t=0
    float wt[8];
    {
        const float* wp = Wb + x * 64 + yo;
        *(float4*)&wt[0] = *(const float4*)(wp);
        *(float4*)&wt[4] = *(const float4*)(wp + 4);
    }

    int cb = 0;
    for (int t = 0; t < 64; ++t) {
        // ---- prefetch W for t+1 (overlaps with LDS + store work) ----
        float wnext[8];
        if (t < 63) {
            const float* wp = Wb + (t + 1) * 4096 + x * 64 + yo;
            *(float4*)&wnext[0] = *(const float4*)(wp);
            *(float4*)&wnext[4] = *(const float4*)(wp + 4);
        }

        float dw[8];
        #pragma unroll
        for (int j = 0; j < 8; ++j)
            dw[j] = (t == 0) ? 0.0f : (wt[j] - wprev[j]) * IDT;
        #pragma unroll
        for (int j = 0; j < 8; ++j) wprev[j] = wt[j];

        // ---- xi-field x-neighbors (state t); xm row doubles as I2 source ----
        float nbm[8], nbp[8];
        *(float4*)&nbm[0] = *(const float4*)&sxi[cb][ldsOff(xm, q0)];
        *(float4*)&nbm[4] = *(const float4*)&sxi[cb][ldsOff(xm, q0 + 1)];
        *(float4*)&nbp[0] = *(const float4*)&sxi[cb][ldsOff(xp, q0)];
        *(float4*)&nbp[4] = *(const float4*)&sxi[cb][ldsOff(xp, q0 + 1)];

        float xi2[8];
        if (x == 0) {   // only wave 0's x==0 lanes take this masked extra read
            *(float4*)&xi2[0] = *(const float4*)&sxi[cb][ldsOff(62, q0)];
            *(float4*)&xi2[4] = *(const float4*)&sxi[cb][ldsOff(62, q0 + 1)];
        } else {
            #pragma unroll
            for (int j = 0; j < 8; ++j) xi2[j] = nbm[j];
        }

        // ---- store the 7 channels at time t (only the owning wave) ----
        if (mine) {
            #pragma unroll
            for (int h = 0; h < 2; ++h) {
                float4 ov[7];
                float* o = (float*)ov;
                #pragma unroll
                for (int j = 0; j < 4; ++j) {
                    const int jj = (h << 2) + j;
                    o[j * 7 + 0] = dw[jj];
                    o[j * 7 + 1] = cxi[jj];
                    o[j * 7 + 2] = (t == 0) ? 0.0f : -xprev[jj];  // I1; t=0 fixed at t=63
                    o[j * 7 + 3] = -xi2[jj];                      // I2
                    o[j * 7 + 4] = c4[jj];
                    o[j * 7 + 5] = c5[jj];
                    o[j * 7 + 6] = c6[jj];
                }
                float4* dst = (float4*)(oB + ((size_t)t * 4096 + x * 64 + yo + (h << 2)) * 7);
                #pragma unroll
                for (int k = 0; k < 7; ++k) dst[k] = ov[k];
            }
        }

        if (t == 63) {
            // deferred: ch2 at t=0 is -I_xi[62] = -xprev (same thread overwrites)
            if (mine) {
                float* p0 = oB + (size_t)(x * 64 + yo) * 7 + 2;
                #pragma unroll
                for (int j = 0; j < 8; ++j) p0[j * 7] = -xprev[j];
            }
        } else {
            const int nb = cb ^ 1;

            // ---- forcings at time t ----
            float g4v[8], g5v[8], g6v[8];
            #pragma unroll
            for (int j = 0; j < 8; ++j) {
                g4v[j] = dw[j] * cxi[j];          // dW * I_xi
                g5v[j] = cxi[j] * cxi[j];         // I_xi^2
                g6v[j] = xprev[j] * xi2[j];       // (-I_xi[t-1]) * (-shift(I_xi[t]))
            }
            #pragma unroll
            for (int j = 0; j < 8; ++j) xprev[j] = cxi[j];

            // ---- one explicit-Euler step per field ----
            auto stepCore = [&](float* c, const float* nm, const float* np_,
                                const float* g) {
                const float ym = __shfl(c[7], laneYm, 64);   // u[x, yo-1] (periodic)
                const float yp = __shfl(c[0], laneYp, 64);   // u[x, yo+8] (periodic)
                float n[8];
                #pragma unroll
                for (int j = 0; j < 8; ++j) {
                    const float left  = (j == 0) ? ym : c[j - 1];
                    const float right = (j == 7) ? yp : c[j + 1];
                    float lap = nm[j] + np_[j] + left + right - 4.0f * c[j];
                    if ((j == 0 && crn0) || (j == 7 && crn7)) lap = 0.0f; // corners
                    n[j] = c[j] + C2 * lap + g[j] * DTC;
                }
                #pragma unroll
                for (int j = 0; j < 8; ++j) c[j] = n[j];
            };
            auto stepField = [&](const float* sArr, float* c, const float* g) {
                float nm[8], np_[8];
                *(float4*)&nm[0]  = *(const float4*)&sArr[ldsOff(xm, q0)];
                *(float4*)&nm[4]  = *(const float4*)&sArr[ldsOff(xm, q0 + 1)];
                *(float4*)&np_[0] = *(const float4*)&sArr[ldsOff(xp, q0)];
                *(float4*)&np_[4] = *(const float4*)&sArr[ldsOff(xp, q0 + 1)];
                stepCore(c, nm, np_, g);
            };

            stepCore (cxi, nbm, nbp, dw);       // xi: neighbors already loaded
            stepField(&s4[cb][0], c4, g4v);
            stepField(&s5[cb][0], c5, g5v);
            stepField(&s6[cb][0], c6, g6v);

            // write state t+1 into the other buffer; single barrier
            #pragma unroll
            for (int h = 0; h < 2; ++h) {
                *(float4*)&sxi[nb][ldsOff(x, q0 + h)] = *(float4*)&cxi[h << 2];
                *(float4*)&s4 [nb][ldsOff(x, q0 + h)] = *(float4*)&c4 [h << 2];
                *(float4*)&s5 [nb][ldsOff(x, q0 + h)] = *(float4*)&c5 [h << 2];
                *(float4*)&s6 [nb][ldsOff(x, q0 + h)] = *(float4*)&c6 [h << 2];
            }
            __syncthreads();
            cb = nb;
        }

        #pragma unroll
        for (int j = 0; j < 8; ++j) wt[j] = wnext[j];
    }
}

} // namespace

extern "C" void kernel_launch(void* const* d_in, const int* in_sizes, int n_in,
                              void* d_out, int out_size, void* d_ws, size_t ws_size,
                              hipStream_t stream) {
    const float* W  = (const float*)d_in[0];
    float* out      = (float*)d_out;
    hipLaunchKernelGGL(fused_scan, dim3(256), dim3(512), 0, stream, W, out);
}